// Round 1
// baseline (647.778 us; speedup 1.0000x reference)
//
#include <hip/hip_runtime.h>

#define Tn 512
#define Bn 2048
#define Dn 2
#define Hn 64
#define NQn 4

__launch_bounds__(64)
__global__ void fraud_lstm_kernel(
    const float* __restrict__ seq,
    const float* __restrict__ Wf, const float* __restrict__ bf, const float* __restrict__ pf,
    const float* __restrict__ Wi, const float* __restrict__ bi, const float* __restrict__ pi,
    const float* __restrict__ Wu, const float* __restrict__ bu, const float* __restrict__ pu,
    const float* __restrict__ Wo, const float* __restrict__ bo, const float* __restrict__ po,
    const float* __restrict__ Wc, const float* __restrict__ bc,
    float* __restrict__ out)
{
    __shared__ float sw[12], w0s[12], w1s[12], kqs[12];
    __shared__ float2 xs[Tn];
    __shared__ float hbuf[Tn];
    __shared__ float sumWc;

    const int tid = threadIdx.x;
    const float* Wg[4] = {Wf, Wi, Wu, Wo};
    const float* bg[4] = {bf, bi, bu, bo};
    const float* pg[4] = {pf, pi, pu, po};

    // Gather x[t] = seq[t, B-1, 0:2] into LDS (strided global loads, all lanes in flight)
    for (int t = tid; t < Tn; t += 64) {
        const float* p = seq + (size_t)t * (Bn * Dn) + (size_t)(Bn - 1) * Dn;
        xs[t] = make_float2(p[0], p[1]);
    }

    // Reduced weights: sw[m] = sum_{j=0..63} Wg[g][(Dn+j)*NQ + q], m = g*3 + (q-1), q in 1..3
    #pragma unroll
    for (int m = 0; m < 12; ++m) {
        const int g = m / 3, q = 1 + (m % 3);
        float v = Wg[g][(Dn + tid) * NQn + q];
        #pragma unroll
        for (int off = 32; off > 0; off >>= 1) v += __shfl_down(v, off, 64);
        if (tid == 0) {
            sw[m]  = v;
            w0s[m] = Wg[g][0 * NQn + q];
            w1s[m] = Wg[g][1 * NQn + q];
            kqs[m] = bg[g][q] + pg[g][q];   // fold bias + phase
        }
    }
    {
        float v = Wc[tid];
        #pragma unroll
        for (int off = 32; off > 0; off >>= 1) v += __shfl_down(v, off, 64);
        if (tid == 0) sumWc = v;
    }
    __syncthreads();

    // Serial scalar recurrence on lane 0 (all H columns of h/c are identical; only batch B-1 is observed)
    if (tid == 0) {
        float W0[12], W1[12], SW[12], KQ[12];
        #pragma unroll
        for (int m = 0; m < 12; ++m) { W0[m] = w0s[m]; W1[m] = w1s[m]; SW[m] = sw[m]; KQ[m] = kqs[m]; }

        float c = 0.f, h = 0.f;
        for (int t = 0; t < Tn; ++t) {
            const float2 x = xs[t];
            float pre[4];
            #pragma unroll
            for (int g = 0; g < 4; ++g) {
                float prod = 1.f;
                #pragma unroll
                for (int j = 0; j < 3; ++j) {
                    const int m = g * 3 + j;
                    const float z = fmaf(x.x, W0[m], fmaf(x.y, W1[m], fmaf(h, SW[m], KQ[m])));
                    prod *= cosf(z);
                }
                pre[g] = prod;
            }
            const float fg = 1.f / (1.f + expf(-pre[0]));
            const float ig = 1.f / (1.f + expf(-pre[1]));
            const float gg = tanhf(pre[2]);
            const float og = 1.f / (1.f + expf(-pre[3]));
            c = fmaf(fg, c, ig * gg);
            h = og * tanhf(c);
            hbuf[t] = h;
        }
    }
    __syncthreads();

    // Epilogue: out[t] = sigmoid(h[t] * sum(Wc) + bc), parallel over lanes
    const float swc = sumWc, b0 = bc[0];
    for (int t = tid; t < Tn; t += 64) {
        out[t] = 1.f / (1.f + expf(-fmaf(hbuf[t], swc, b0)));
    }
}

extern "C" void kernel_launch(void* const* d_in, const int* in_sizes, int n_in,
                              void* d_out, int out_size, void* d_ws, size_t ws_size,
                              hipStream_t stream) {
    const float* seq = (const float*)d_in[0];
    const float* Wf  = (const float*)d_in[1];
    const float* bf  = (const float*)d_in[2];
    const float* pf  = (const float*)d_in[3];
    const float* Wi  = (const float*)d_in[4];
    const float* bi  = (const float*)d_in[5];
    const float* pi  = (const float*)d_in[6];
    const float* Wu  = (const float*)d_in[7];
    const float* bu  = (const float*)d_in[8];
    const float* pu  = (const float*)d_in[9];
    const float* Wo  = (const float*)d_in[10];
    const float* bo  = (const float*)d_in[11];
    const float* po  = (const float*)d_in[12];
    const float* Wc  = (const float*)d_in[13];
    const float* bc  = (const float*)d_in[14];
    float* out = (float*)d_out;

    fraud_lstm_kernel<<<1, 64, 0, stream>>>(seq, Wf, bf, pf, Wi, bi, pi,
                                            Wu, bu, pu, Wo, bo, po, Wc, bc, out);
}

// Round 2
// 130.515 us; speedup vs baseline: 4.9632x; 4.9632x over previous
//
#include <hip/hip_runtime.h>

#define Tn 512
#define Bn 2048
#define Dn 2
#define Hn 64
#define NQn 4

#define INV2PI 0.15915494309189535f   // 1/(2*pi)
#define L2E    1.4426950408889634f    // log2(e)

// sigmoid(x) = 1/(1+e^-x) via hw exp2 + rcp
__device__ __forceinline__ float fsig(float x) {
    return __builtin_amdgcn_rcpf(1.f + __builtin_amdgcn_exp2f(-x * L2E));
}
// tanh(x) = 1 - 2/(e^{2x}+1) via hw exp2 + rcp
__device__ __forceinline__ float ftanh(float x) {
    return 1.f - 2.f * __builtin_amdgcn_rcpf(1.f + __builtin_amdgcn_exp2f(x * (2.f * L2E)));
}
// cos(2*pi*r) for r in revolutions, periodic-reduced via fract
__device__ __forceinline__ float fcos_rev(float r) {
    return __builtin_amdgcn_cosf(__builtin_amdgcn_fractf(r));
}

__launch_bounds__(64)
__global__ void fraud_lstm_kernel(
    const float* __restrict__ seq,
    const float* __restrict__ Wf, const float* __restrict__ bf, const float* __restrict__ pf,
    const float* __restrict__ Wi, const float* __restrict__ bi, const float* __restrict__ pi,
    const float* __restrict__ Wu, const float* __restrict__ bu, const float* __restrict__ pu,
    const float* __restrict__ Wo, const float* __restrict__ bo, const float* __restrict__ po,
    const float* __restrict__ Wc, const float* __restrict__ bc,
    float* __restrict__ out)
{
    __shared__ float sw[12], w0s[12], w1s[12], kqs[12];
    __shared__ float2 xs[Tn];
    __shared__ float hbuf[Tn];
    __shared__ float zb[Tn][12];   // (x-part of z + bias + phase) / (2*pi), per (t, gate*3+j)
    __shared__ float sumWc;

    const int tid = threadIdx.x;
    const float* Wg[4] = {Wf, Wi, Wu, Wo};
    const float* bg[4] = {bf, bi, bu, bo};
    const float* pg[4] = {pf, pi, pu, po};

    // Gather x[t] = seq[t, B-1, 0:2] into LDS
    for (int t = tid; t < Tn; t += 64) {
        const float* p = seq + (size_t)t * (Bn * Dn) + (size_t)(Bn - 1) * Dn;
        xs[t] = make_float2(p[0], p[1]);
    }

    // Reduced weights: sw[m] = sum_{j=0..63} Wg[g][(Dn+j)*NQ + q], m = g*3 + (q-1), q in 1..3
    #pragma unroll
    for (int m = 0; m < 12; ++m) {
        const int g = m / 3, q = 1 + (m % 3);
        float v = Wg[g][(Dn + tid) * NQn + q];
        #pragma unroll
        for (int off = 32; off > 0; off >>= 1) v += __shfl_down(v, off, 64);
        if (tid == 0) {
            sw[m]  = v * INV2PI;                 // pre-scale to revolutions
            w0s[m] = Wg[g][0 * NQn + q];
            w1s[m] = Wg[g][1 * NQn + q];
            kqs[m] = bg[g][q] + pg[g][q];        // fold bias + phase
        }
    }
    {
        float v = Wc[tid];
        #pragma unroll
        for (int off = 32; off > 0; off >>= 1) v += __shfl_down(v, off, 64);
        if (tid == 0) sumWc = v;
    }
    __syncthreads();

    // Parallel precompute of the h-independent part of every gate pre-activation
    for (int t = tid; t < Tn; t += 64) {
        const float2 x = xs[t];
        #pragma unroll
        for (int m = 0; m < 12; ++m) {
            zb[t][m] = fmaf(x.x, w0s[m], fmaf(x.y, w1s[m], kqs[m])) * INV2PI;
        }
    }
    __syncthreads();

    // Serial scalar recurrence on lane 0 (hw transcendentals; z kept in revolutions)
    if (tid == 0) {
        float SWs[12];
        #pragma unroll
        for (int m = 0; m < 12; ++m) SWs[m] = sw[m];

        float c = 0.f, h = 0.f;
        for (int t = 0; t < Tn; ++t) {
            const float* z = zb[t];
            float pre[4];
            #pragma unroll
            for (int g = 0; g < 4; ++g) {
                float p0 = fcos_rev(fmaf(h, SWs[g * 3 + 0], z[g * 3 + 0]));
                float p1 = fcos_rev(fmaf(h, SWs[g * 3 + 1], z[g * 3 + 1]));
                float p2 = fcos_rev(fmaf(h, SWs[g * 3 + 2], z[g * 3 + 2]));
                pre[g] = p0 * p1 * p2;
            }
            const float fg = fsig(pre[0]);
            const float ig = fsig(pre[1]);
            const float gg = ftanh(pre[2]);
            const float og = fsig(pre[3]);
            c = fmaf(fg, c, ig * gg);
            h = og * ftanh(c);
            hbuf[t] = h;
        }
    }
    __syncthreads();

    // Epilogue: out[t] = sigmoid(h[t] * sum(Wc) + bc)
    const float swc = sumWc, b0 = bc[0];
    for (int t = tid; t < Tn; t += 64) {
        out[t] = fsig(fmaf(hbuf[t], swc, b0));
    }
}

extern "C" void kernel_launch(void* const* d_in, const int* in_sizes, int n_in,
                              void* d_out, int out_size, void* d_ws, size_t ws_size,
                              hipStream_t stream) {
    const float* seq = (const float*)d_in[0];
    const float* Wf  = (const float*)d_in[1];
    const float* bf  = (const float*)d_in[2];
    const float* pf  = (const float*)d_in[3];
    const float* Wi  = (const float*)d_in[4];
    const float* bi  = (const float*)d_in[5];
    const float* pi  = (const float*)d_in[6];
    const float* Wu  = (const float*)d_in[7];
    const float* bu  = (const float*)d_in[8];
    const float* pu  = (const float*)d_in[9];
    const float* Wo  = (const float*)d_in[10];
    const float* bo  = (const float*)d_in[11];
    const float* po  = (const float*)d_in[12];
    const float* Wc  = (const float*)d_in[13];
    const float* bc  = (const float*)d_in[14];
    float* out = (float*)d_out;

    fraud_lstm_kernel<<<1, 64, 0, stream>>>(seq, Wf, bf, pf, Wi, bi, pi,
                                            Wu, bu, pu, Wo, bo, po, Wc, bc, out);
}

// Round 5
// 60.854 us; speedup vs baseline: 10.6449x; 2.1447x over previous
//
#include <hip/hip_runtime.h>

#define Tn 512
#define Bn 2048
#define Dn 2
#define NQn 4

#define INV2PI 0.15915494309189535f   // 1/(2*pi)
#define L2E    1.4426950408889634f    // log2(e)

__device__ __forceinline__ float fsig_hw(float x) {
    return __builtin_amdgcn_rcpf(1.f + __builtin_amdgcn_exp2f(-x * L2E));
}
__device__ __forceinline__ float ftanh_hw(float x) {
    return 1.f - 2.f * __builtin_amdgcn_rcpf(1.f + __builtin_amdgcn_exp2f(x * (2.f * L2E)));
}
// full-rate DPP permute; CTRL 0x00-0xFF = quad_perm, 0x121-0x12F = row_ror
template<int CTRL>
__device__ __forceinline__ float dppf(float x) {
    return __int_as_float(__builtin_amdgcn_mov_dpp(__float_as_int(x), CTRL, 0xF, 0xF, true));
}

__launch_bounds__(64)
__global__ void fraud_lstm_kernel(
    const float* __restrict__ seq,
    const float* __restrict__ Wf, const float* __restrict__ bf, const float* __restrict__ pf,
    const float* __restrict__ Wi, const float* __restrict__ bi, const float* __restrict__ pi,
    const float* __restrict__ Wu, const float* __restrict__ bu, const float* __restrict__ pu,
    const float* __restrict__ Wo, const float* __restrict__ bo, const float* __restrict__ po,
    const float* __restrict__ Wc, const float* __restrict__ bc,
    float* __restrict__ out)
{
    __shared__ float swArr[12], w0s[12], w1s[12], kqs[12];
    __shared__ float2 xs[Tn];
    __shared__ float zbuf[(Tn + 2) * 16];   // z-base per (t, lane16 = j*4+g), revolutions; j==3 slots = 0
    __shared__ float hbuf[Tn];
    __shared__ float sumWc;

    const int tid = threadIdx.x;
    const float* Wg[4] = {Wf, Wi, Wu, Wo};
    const float* bg[4] = {bf, bi, bu, bo};
    const float* pg[4] = {pf, pi, pu, po};

    // ---- stage x[t] = seq[t, B-1, 0:2] into LDS ----
    for (int t = tid; t < Tn; t += 64) {
        const float* p = seq + (size_t)t * (Bn * Dn) + (size_t)(Bn - 1) * Dn;
        xs[t] = make_float2(p[0], p[1]);
    }

    // ---- reduce weights: swArr[m] = (sum_j Wg[g][(Dn+j)*NQ+q]) / 2pi, m = g*3+(q-1) ----
    #pragma unroll
    for (int m = 0; m < 12; ++m) {
        const int g = m / 3, q = 1 + (m % 3);
        float v = Wg[g][(Dn + tid) * NQn + q];
        #pragma unroll
        for (int off = 32; off > 0; off >>= 1) v += __shfl_down(v, off, 64);
        if (tid == 0) {
            swArr[m] = v * INV2PI;
            w0s[m]   = Wg[g][0 * NQn + q];
            w1s[m]   = Wg[g][1 * NQn + q];
            kqs[m]   = bg[g][q] + pg[g][q];
        }
    }
    {
        float v = Wc[tid];
        #pragma unroll
        for (int off = 32; off > 0; off >>= 1) v += __shfl_down(v, off, 64);
        if (tid == 0) sumWc = v;
    }
    __syncthreads();

    // ---- parallel precompute zbuf: column m16 = j*4 + g (gate g in quad position) ----
    {
        const int m16 = tid & 15;
        const int g2 = m16 & 3, j2 = m16 >> 2;
        const int mm = g2 * 3 + j2;          // valid only when j2<3
        const bool live = (j2 < 3);
        const float w0 = live ? w0s[mm] : 0.f;
        const float w1 = live ? w1s[mm] : 0.f;
        const float kq = live ? kqs[mm] : 0.f;
        for (int t0 = (tid >> 4); t0 < Tn; t0 += 4) {
            const float2 x = xs[t0];
            zbuf[t0 * 16 + m16] = live ? fmaf(x.x, w0, fmaf(x.y, w1, kq)) * INV2PI : 0.f;
        }
    }
    __syncthreads();

    // ---- serial recurrence, whole wave cooperates; h,c wave-uniform ----
    {
        const int l16 = tid & 15;
        const int g  = l16 & 3;        // gate = quad position
        const int jj = l16 >> 2;       // cos slot = quad index within row
        const float SWl = (jj < 3) ? swArr[g * 3 + jj] : 0.f;
        const bool isG2 = (g == 2);
        // unified nonlinearity: r = rcp(1+exp2(pre*sscl)); A = fmaf(mulA, r, addA)
        //   sigmoid lanes: sscl=-L2E, A=r ; tanh lane (g==2): sscl=2*L2E, A=1-2r
        const float sscl = isG2 ? (2.f * L2E) : (-L2E);
        const float mulA = isG2 ? -2.f : 1.f;
        const float addA = isG2 ? 1.f : 0.f;

        float h = 0.f, c = 0.f;
        int zoff = l16;
        float zc = zbuf[zoff];          // t = 0
        float zn = zbuf[zoff + 16];     // t = 1
        float hsave = 0.f;

        for (int blk = 0; blk < 8; ++blk) {
            for (int t64 = 0; t64 < 64; ++t64) {
                const float zf = zbuf[zoff + 32];   // prefetch t+2 (padded)
                zoff += 16;
                // z in revolutions; dead slots (jj==3): z=0 -> cos=1
                const float z  = fmaf(h, SWl, zc);
                const float pc = __builtin_amdgcn_cosf(__builtin_amdgcn_fractf(z));
                // product over the 4 j-slots (same quad position g across the row):
                // row_ror +/-4 then +/-8 covers all j regardless of rotation direction
                const float p1  = pc * dppf<0x124>(pc);  // j, j +/- 1
                const float pre = p1 * dppf<0x128>(p1);  // full product over j
                // own-gate nonlinearity via hw exp2+rcp (bit-matches R1 path)
                const float r  = __builtin_amdgcn_rcpf(1.f + __builtin_amdgcn_exp2f(pre * sscl));
                const float A  = fmaf(mulA, r, addA);
                // gather gates by quad broadcast (explicit encodings, direction-free)
                const float f  = dppf<0x00>(A);          // quad lane 0 = gate f
                const float i  = dppf<0x55>(A);          // quad lane 1 = gate i
                const float gu = dppf<0xAA>(A);          // quad lane 2 = gate u (tanh)
                const float o  = dppf<0xFF>(A);          // quad lane 3 = gate o
                c = fmaf(f, c, i * gu);
                h = o * ftanh_hw(c);
                hsave = (tid == t64) ? h : hsave;
                zc = zn; zn = zf;
            }
            hbuf[blk * 64 + tid] = hsave;
        }
    }
    __syncthreads();

    // ---- epilogue: out[t] = sigmoid(h[t]*sum(Wc) + bc) ----
    const float swc = sumWc, b0 = bc[0];
    for (int t = tid; t < Tn; t += 64) {
        out[t] = fsig_hw(fmaf(hbuf[t], swc, b0));
    }
}

extern "C" void kernel_launch(void* const* d_in, const int* in_sizes, int n_in,
                              void* d_out, int out_size, void* d_ws, size_t ws_size,
                              hipStream_t stream) {
    const float* seq = (const float*)d_in[0];
    const float* Wf  = (const float*)d_in[1];
    const float* bf  = (const float*)d_in[2];
    const float* pf  = (const float*)d_in[3];
    const float* Wi  = (const float*)d_in[4];
    const float* bi  = (const float*)d_in[5];
    const float* pi  = (const float*)d_in[6];
    const float* Wu  = (const float*)d_in[7];
    const float* bu  = (const float*)d_in[8];
    const float* pu  = (const float*)d_in[9];
    const float* Wo  = (const float*)d_in[10];
    const float* bo  = (const float*)d_in[11];
    const float* po  = (const float*)d_in[12];
    const float* Wc  = (const float*)d_in[13];
    const float* bc  = (const float*)d_in[14];
    float* out = (float*)d_out;

    fraud_lstm_kernel<<<1, 64, 0, stream>>>(seq, Wf, bf, pf, Wi, bi, pi,
                                            Wu, bu, pu, Wo, bo, po, Wc, bc, out);
}

// Round 6
// 60.257 us; speedup vs baseline: 10.7503x; 1.0099x over previous
//
#include <hip/hip_runtime.h>

#define Tn 512
#define Bn 2048
#define Dn 2
#define NQn 4

#define INV2PI 0.15915494309189535f   // 1/(2*pi)
#define L2E    1.4426950408889634f    // log2(e)

__device__ __forceinline__ float fsig_hw(float x) {
    return __builtin_amdgcn_rcpf(1.f + __builtin_amdgcn_exp2f(-x * L2E));
}
// full-rate DPP permute; CTRL 0x00-0xFF = quad_perm, 0x121-0x12F = row_ror
template<int CTRL>
__device__ __forceinline__ float dppf(float x) {
    return __int_as_float(__builtin_amdgcn_mov_dpp(__float_as_int(x), CTRL, 0xF, 0xF, true));
}

__launch_bounds__(64)
__global__ void fraud_lstm_kernel(
    const float* __restrict__ seq,
    const float* __restrict__ Wf, const float* __restrict__ bf, const float* __restrict__ pf,
    const float* __restrict__ Wi, const float* __restrict__ bi, const float* __restrict__ pi,
    const float* __restrict__ Wu, const float* __restrict__ bu, const float* __restrict__ pu,
    const float* __restrict__ Wo, const float* __restrict__ bo, const float* __restrict__ po,
    const float* __restrict__ Wc, const float* __restrict__ bc,
    float* __restrict__ out)
{
    __shared__ float swArr[12], w0s[12], w1s[12], kqs[12];
    __shared__ float2 xs[Tn];
    __shared__ float zbuf[(Tn + 2) * 16];   // z-base per (t, lane16 = j*4+g), revolutions; j==3 slots = 0
    __shared__ float hbuf[Tn];
    __shared__ float sumWc;

    const int tid = threadIdx.x;
    const float* Wg[4] = {Wf, Wi, Wu, Wo};
    const float* bg[4] = {bf, bi, bu, bo};
    const float* pg[4] = {pf, pi, pu, po};

    // ---- stage x[t] = seq[t, B-1, 0:2] into LDS ----
    for (int t = tid; t < Tn; t += 64) {
        const float* p = seq + (size_t)t * (Bn * Dn) + (size_t)(Bn - 1) * Dn;
        xs[t] = make_float2(p[0], p[1]);
    }

    // ---- reduce weights: swArr[m] = (sum_j Wg[g][(Dn+j)*NQ+q]) / 2pi, m = g*3+(q-1) ----
    #pragma unroll
    for (int m = 0; m < 12; ++m) {
        const int g = m / 3, q = 1 + (m % 3);
        float v = Wg[g][(Dn + tid) * NQn + q];
        #pragma unroll
        for (int off = 32; off > 0; off >>= 1) v += __shfl_down(v, off, 64);
        if (tid == 0) {
            swArr[m] = v * INV2PI;
            w0s[m]   = Wg[g][0 * NQn + q];
            w1s[m]   = Wg[g][1 * NQn + q];
            kqs[m]   = bg[g][q] + pg[g][q];
        }
    }
    {
        float v = Wc[tid];
        #pragma unroll
        for (int off = 32; off > 0; off >>= 1) v += __shfl_down(v, off, 64);
        if (tid == 0) sumWc = v;
    }
    __syncthreads();

    // ---- parallel precompute zbuf: column m16 = j*4 + g (gate g in quad position) ----
    {
        const int m16 = tid & 15;
        const int g2 = m16 & 3, j2 = m16 >> 2;
        const int mm = g2 * 3 + j2;          // valid only when j2<3
        const bool live = (j2 < 3);
        const float w0 = live ? w0s[mm] : 0.f;
        const float w1 = live ? w1s[mm] : 0.f;
        const float kq = live ? kqs[mm] : 0.f;
        for (int t0 = (tid >> 4); t0 < Tn; t0 += 4) {
            const float2 x = xs[t0];
            zbuf[t0 * 16 + m16] = live ? fmaf(x.x, w0, fmaf(x.y, w1, kq)) * INV2PI : 0.f;
        }
    }
    __syncthreads();

    // ---- serial recurrence, whole wave cooperates; h,c wave-uniform ----
    // Nonlinearities via Pade continued-fraction rationals (1 rcp each, no exp2):
    //   gate: sigma(x) = 0.5 + 0.5*tanh(x/2); tanh(u) ~ u*(945+105y+y^2)/(945+420y+15y^2), y=u^2 (|u|<=1, err<1e-7)
    //   cell: tanh(c)  ~ c*(10395+1260y+21y^2)/(10395+4725y+210y^2+y^3), y=c^2 (|c|<=2.1, err~1e-6)
    {
        const int l16 = tid & 15;
        const int g  = l16 & 3;        // gate = quad position
        const int jj = l16 >> 2;       // cos slot = quad index within row
        const float SWl = (jj < 3) ? swArr[g * 3 + jj] : 0.f;
        const bool isG2 = (g == 2);
        const float uscale = isG2 ? 1.f : 0.5f;   // tanh arg scale (x/2 for sigmoid lanes)
        const float pscale = isG2 ? 1.f : 0.5f;   // output scale (0.5*tanh for sigmoid lanes)
        const float addA   = isG2 ? 0.f : 0.5f;   // +0.5 for sigmoid lanes

        float c = 0.f;
        int zoff = l16;
        float zacc = zbuf[zoff];        // z(0) = base(0) since h(-1)=0
        float zn   = zbuf[zoff + 16];   // base(1)
        float hsave = 0.f;

        for (int blk = 0; blk < 8; ++blk) {
            for (int t64 = 0; t64 < 64; ++t64) {
                const float zf = zbuf[zoff + 32];   // prefetch base(t+2) (padded)
                zoff += 16;
                // z in revolutions; dead slots (jj==3): z=0 -> cos=1
                const float pc = __builtin_amdgcn_cosf(__builtin_amdgcn_fractf(zacc));
                // product of the 4 j-slot cosines (commutative over row_ror direction)
                const float p1 = pc * dppf<0x124>(pc);           // j, j+/-1
                const float u  = (p1 * uscale) * dppf<0x128>(p1); // scaled full product
                // gate nonlinearity: rational tanh(u)
                const float y   = u * u;
                const float Qg  = fmaf(y, fmaf(y, 15.f, 420.f), 945.f);
                const float Pg  = fmaf(y, (105.f + y), 945.f);
                const float rQ  = __builtin_amdgcn_rcpf(Qg);
                const float uPs = (u * pscale) * Pg;
                const float A   = fmaf(uPs, rQ, addA);
                // gather gates by quad broadcast
                const float f  = dppf<0x00>(A);
                const float i  = dppf<0x55>(A);
                const float gu = dppf<0xAA>(A);
                const float o  = dppf<0xFF>(A);
                c = fmaf(f, c, i * gu);
                // cell tanh via depth-6 Pade; fuse h into next z: chain from rcp is one fma
                const float y2  = c * c;
                const float Q2  = fmaf(y2, fmaf(y2, fmaf(y2, 1.f, 210.f), 4725.f), 10395.f);
                const float P2  = fmaf(y2, fmaf(y2, 21.f, 1260.f), 10395.f);
                const float rQ2 = __builtin_amdgcn_rcpf(Q2);
                const float ocP = (o * c) * P2;     // off-chain (parallel with rcp)
                const float m   = ocP * SWl;        // off-chain, per-lane
                zacc = fmaf(m, rQ2, zn);            // z(t+1) = h*SWl + base(t+1)
                const float h = ocP * rQ2;          // off-chain, for output only
                hsave = (tid == t64) ? h : hsave;
                zn = zf;
            }
            hbuf[blk * 64 + tid] = hsave;
        }
    }
    __syncthreads();

    // ---- epilogue: out[t] = sigmoid(h[t]*sum(Wc) + bc) ----
    const float swc = sumWc, b0 = bc[0];
    for (int t = tid; t < Tn; t += 64) {
        out[t] = fsig_hw(fmaf(hbuf[t], swc, b0));
    }
}

extern "C" void kernel_launch(void* const* d_in, const int* in_sizes, int n_in,
                              void* d_out, int out_size, void* d_ws, size_t ws_size,
                              hipStream_t stream) {
    const float* seq = (const float*)d_in[0];
    const float* Wf  = (const float*)d_in[1];
    const float* bf  = (const float*)d_in[2];
    const float* pf  = (const float*)d_in[3];
    const float* Wi  = (const float*)d_in[4];
    const float* bi  = (const float*)d_in[5];
    const float* pi  = (const float*)d_in[6];
    const float* Wu  = (const float*)d_in[7];
    const float* bu  = (const float*)d_in[8];
    const float* pu  = (const float*)d_in[9];
    const float* Wo  = (const float*)d_in[10];
    const float* bo  = (const float*)d_in[11];
    const float* po  = (const float*)d_in[12];
    const float* Wc  = (const float*)d_in[13];
    const float* bc  = (const float*)d_in[14];
    float* out = (float*)d_out;

    fraud_lstm_kernel<<<1, 64, 0, stream>>>(seq, Wf, bf, pf, Wi, bi, pi,
                                            Wu, bu, pu, Wo, bo, po, Wc, bc, out);
}

// Round 7
// 58.169 us; speedup vs baseline: 11.1361x; 1.0359x over previous
//
#include <hip/hip_runtime.h>

#define Tn 512
#define Bn 2048
#define Dn 2
#define NQn 4

#define INV2PI 0.15915494309189535f   // 1/(2*pi)
#define L2E    1.4426950408889634f    // log2(e)

__device__ __forceinline__ float fsig_hw(float x) {
    return __builtin_amdgcn_rcpf(1.f + __builtin_amdgcn_exp2f(-x * L2E));
}
// full-rate DPP permute; CTRL 0x00-0xFF = quad_perm, 0x121-0x12F = row_ror
template<int CTRL>
__device__ __forceinline__ float dppf(float x) {
    return __int_as_float(__builtin_amdgcn_mov_dpp(__float_as_int(x), CTRL, 0xF, 0xF, true));
}

__launch_bounds__(64)
__global__ void fraud_lstm_kernel(
    const float* __restrict__ seq,
    const float* __restrict__ Wf, const float* __restrict__ bf, const float* __restrict__ pf,
    const float* __restrict__ Wi, const float* __restrict__ bi, const float* __restrict__ pi,
    const float* __restrict__ Wu, const float* __restrict__ bu, const float* __restrict__ pu,
    const float* __restrict__ Wo, const float* __restrict__ bo, const float* __restrict__ po,
    const float* __restrict__ Wc, const float* __restrict__ bc,
    float* __restrict__ out)
{
    __shared__ float swArr[12], w0s[12], w1s[12], kqs[12];
    __shared__ float2 xs[Tn];
    __shared__ float zbuf[(Tn + 2) * 16];   // z-base per (t, lane16 = j*4+g), revolutions; j==3 slots = 0
    __shared__ float hbuf[Tn];
    __shared__ float sumWc;

    const int tid = threadIdx.x;
    const float* Wg[4] = {Wf, Wi, Wu, Wo};
    const float* bg[4] = {bf, bi, bu, bo};
    const float* pg[4] = {pf, pi, pu, po};

    // ---- stage x[t] = seq[t, B-1, 0:2] into LDS ----
    for (int t = tid; t < Tn; t += 64) {
        const float* p = seq + (size_t)t * (Bn * Dn) + (size_t)(Bn - 1) * Dn;
        xs[t] = make_float2(p[0], p[1]);
    }

    // ---- reduce weights: swArr[m] = (sum_j Wg[g][(Dn+j)*NQ+q]) / 2pi, m = g*3+(q-1) ----
    #pragma unroll
    for (int m = 0; m < 12; ++m) {
        const int g = m / 3, q = 1 + (m % 3);
        float v = Wg[g][(Dn + tid) * NQn + q];
        #pragma unroll
        for (int off = 32; off > 0; off >>= 1) v += __shfl_down(v, off, 64);
        if (tid == 0) {
            swArr[m] = v * INV2PI;
            w0s[m]   = Wg[g][0 * NQn + q];
            w1s[m]   = Wg[g][1 * NQn + q];
            kqs[m]   = bg[g][q] + pg[g][q];
        }
    }
    {
        float v = Wc[tid];
        #pragma unroll
        for (int off = 32; off > 0; off >>= 1) v += __shfl_down(v, off, 64);
        if (tid == 0) sumWc = v;
    }
    __syncthreads();

    // ---- parallel precompute zbuf: column m16 = j*4 + g (gate g in quad position) ----
    {
        const int m16 = tid & 15;
        const int g2 = m16 & 3, j2 = m16 >> 2;
        const int mm = g2 * 3 + j2;          // valid only when j2<3
        const bool live = (j2 < 3);
        const float w0 = live ? w0s[mm] : 0.f;
        const float w1 = live ? w1s[mm] : 0.f;
        const float kq = live ? kqs[mm] : 0.f;
        for (int t0 = (tid >> 4); t0 < Tn; t0 += 4) {
            const float2 x = xs[t0];
            zbuf[t0 * 16 + m16] = live ? fmaf(x.x, w0, fmaf(x.y, w1, kq)) * INV2PI : 0.f;
        }
    }
    __syncthreads();

    // ---- serial recurrence, whole wave cooperates; h,c wave-uniform ----
    // Gate nonlinearity, per-lane [3/3] Pade in w = u^2 (u = cos-product):
    //   sigmoid lanes: sigma(u) = 0.5 + u*(945+26.25w+0.0625w^2)/(3780+420w+3.75w^2)   (err < 2e-7)
    //   tanh lane    : tanh(u)  =       u*(945+105w +w^2)      /(945 +420w+15w^2)      (err < 1e-7)
    // Cell tanh [3/3], SWl folded into numerator coeffs so the chain tail is one fma.
    {
        const int l16 = tid & 15;
        const int g  = l16 & 3;        // gate = quad position
        const int jj = l16 >> 2;       // cos slot = quad index within row
        const float SWl = (jj < 3) ? swArr[g * 3 + jj] : 0.f;
        const bool isG2 = (g == 2);
        const float cp0 = isG2 ? 945.f : 945.f;
        const float cp1 = isG2 ? 105.f : 26.25f;
        const float cp2 = isG2 ? 1.f   : 0.0625f;
        const float cq0 = isG2 ? 945.f : 3780.f;
        const float cq1 = isG2 ? 420.f : 420.f;
        const float cq2 = isG2 ? 15.f  : 3.75f;
        const float addA = isG2 ? 0.f  : 0.5f;
        // cell-tanh numerator coeffs with SWl folded in
        const float s0 = 10395.f * SWl, s1 = 1260.f * SWl, s2 = 21.f * SWl;

        float c = 0.f;
        int zoff = l16;
        float zacc = zbuf[zoff];        // z(0) = base(0) since h(-1)=0
        float zn   = zbuf[zoff + 16];   // base(1)
        float hsave = 0.f;

        for (int blk = 0; blk < 8; ++blk) {
            #pragma unroll 32
            for (int t64 = 0; t64 < 64; ++t64) {
                const float zf = zbuf[zoff + 32];   // prefetch base(t+2) (padded)
                zoff += 16;
                // z in revolutions; gfx9+ v_cos range-reduces in HW (no fract needed)
                const float pc = __builtin_amdgcn_cosf(zacc);
                // product of the 4 j-slot cosines (dead slot z=0 -> cos=1)
                const float p1v = pc * dppf<0x124>(pc);
                const float u   = p1v * dppf<0x128>(p1v);
                // gate nonlinearity: per-lane rational
                const float w   = u * u;
                const float wsq = w * w;
                const float Pn  = fmaf(wsq, cp2, fmaf(w, cp1, cp0));
                const float Qd  = fmaf(wsq, cq2, fmaf(w, cq1, cq0));
                const float rQ  = __builtin_amdgcn_rcpf(Qd);
                const float uP  = u * Pn;
                const float A   = fmaf(uP, rQ, addA);
                // gather gates by quad broadcast
                const float fg = dppf<0x00>(A);
                const float ig = dppf<0x55>(A);
                const float gu = dppf<0xAA>(A);
                const float og = dppf<0xFF>(A);
                c = fmaf(fg, c, ig * gu);
                // cell tanh [3/3], Estrin; chain tail = single fma into zacc
                const float y2   = c * c;
                const float y2sq = y2 * y2;
                const float oc   = og * c;
                const float P2S  = fmaf(y2sq, s2, fmaf(y2, s1, s0));       // SWl-scaled numerator
                const float Q2   = fmaf(y2sq, (y2 + 210.f), fmaf(y2, 4725.f, 10395.f));
                const float rQ2  = __builtin_amdgcn_rcpf(Q2);
                const float mP   = oc * P2S;
                zacc = fmaf(mP, rQ2, zn);            // z(t+1) = h*SWl + base(t+1)
                // h for output (off the critical chain)
                const float P2   = fmaf(y2sq, 21.f, fmaf(y2, 1260.f, 10395.f));
                const float h    = (oc * P2) * rQ2;
                hsave = (tid == t64) ? h : hsave;
                zn = zf;
            }
            hbuf[blk * 64 + tid] = hsave;
        }
    }
    __syncthreads();

    // ---- epilogue: out[t] = sigmoid(h[t]*sum(Wc) + bc) ----
    const float swc = sumWc, b0 = bc[0];
    for (int t = tid; t < Tn; t += 64) {
        out[t] = fsig_hw(fmaf(hbuf[t], swc, b0));
    }
}

extern "C" void kernel_launch(void* const* d_in, const int* in_sizes, int n_in,
                              void* d_out, int out_size, void* d_ws, size_t ws_size,
                              hipStream_t stream) {
    const float* seq = (const float*)d_in[0];
    const float* Wf  = (const float*)d_in[1];
    const float* bf  = (const float*)d_in[2];
    const float* pf  = (const float*)d_in[3];
    const float* Wi  = (const float*)d_in[4];
    const float* bi  = (const float*)d_in[5];
    const float* pi  = (const float*)d_in[6];
    const float* Wu  = (const float*)d_in[7];
    const float* bu  = (const float*)d_in[8];
    const float* pu  = (const float*)d_in[9];
    const float* Wo  = (const float*)d_in[10];
    const float* bo  = (const float*)d_in[11];
    const float* po  = (const float*)d_in[12];
    const float* Wc  = (const float*)d_in[13];
    const float* bc  = (const float*)d_in[14];
    float* out = (float*)d_out;

    fraud_lstm_kernel<<<1, 64, 0, stream>>>(seq, Wf, bf, pf, Wi, bi, pi,
                                            Wu, bu, pu, Wo, bo, po, Wc, bc, out);
}

// Round 8
// 57.921 us; speedup vs baseline: 11.1839x; 1.0043x over previous
//
#include <hip/hip_runtime.h>

#define Tn 512
#define Bn 2048
#define Dn 2
#define NQn 4

#define INV2PI 0.15915494309189535f   // 1/(2*pi)
#define L2E    1.4426950408889634f    // log2(e)

__device__ __forceinline__ float fsig_hw(float x) {
    return __builtin_amdgcn_rcpf(1.f + __builtin_amdgcn_exp2f(-x * L2E));
}
// full-rate DPP permute; CTRL 0x00-0xFF = quad_perm, 0x121-0x12F = row_ror
template<int CTRL>
__device__ __forceinline__ float dppf(float x) {
    return __int_as_float(__builtin_amdgcn_mov_dpp(__float_as_int(x), CTRL, 0xF, 0xF, true));
}

__launch_bounds__(64)
__global__ void fraud_lstm_kernel(
    const float* __restrict__ seq,
    const float* __restrict__ Wf, const float* __restrict__ bf, const float* __restrict__ pf,
    const float* __restrict__ Wi, const float* __restrict__ bi, const float* __restrict__ pi,
    const float* __restrict__ Wu, const float* __restrict__ bu, const float* __restrict__ pu,
    const float* __restrict__ Wo, const float* __restrict__ bo, const float* __restrict__ po,
    const float* __restrict__ Wc, const float* __restrict__ bc,
    float* __restrict__ out)
{
    __shared__ float swArr[12], w0s[12], w1s[12], kqs[12];
    __shared__ float invSW16[16];
    __shared__ float2 xs[Tn];
    __shared__ float zbuf[(Tn + 2) * 16];   // z-base per (t, lane16 = j*4+g), revolutions
    __shared__ float zsaveA[Tn];            // saved zacc, steps with (t&15)<12
    __shared__ float zsaveB[Tn + 8];        // saved zacc, steps with (t&15)>=12 (saved by lane t-4)
    __shared__ float sumWc;

    const int tid = threadIdx.x;
    const float* Wg[4] = {Wf, Wi, Wu, Wo};
    const float* bg[4] = {bf, bi, bu, bo};
    const float* pg[4] = {pf, pi, pu, po};

    // ---- stage x[t] = seq[t, B-1, 0:2] into LDS ----
    for (int t = tid; t < Tn; t += 64) {
        const float* p = seq + (size_t)t * (Bn * Dn) + (size_t)(Bn - 1) * Dn;
        xs[t] = make_float2(p[0], p[1]);
    }

    // ---- reduce weights: swArr[m] = (sum_j Wg[g][(Dn+j)*NQ+q]) / 2pi, m = g*3+(q-1) ----
    #pragma unroll
    for (int m = 0; m < 12; ++m) {
        const int g = m / 3, q = 1 + (m % 3);
        float v = Wg[g][(Dn + tid) * NQn + q];
        #pragma unroll
        for (int off = 32; off > 0; off >>= 1) v += __shfl_down(v, off, 64);
        if (tid == 0) {
            swArr[m] = v * INV2PI;
            w0s[m]   = Wg[g][0 * NQn + q];
            w1s[m]   = Wg[g][1 * NQn + q];
            kqs[m]   = bg[g][q] + pg[g][q];
        }
    }
    {
        float v = Wc[tid];
        #pragma unroll
        for (int off = 32; off > 0; off >>= 1) v += __shfl_down(v, off, 64);
        if (tid == 0) sumWc = v;
    }
    __syncthreads();

    // ---- parallel precompute zbuf: column m16 = j*4 + g (gate g in quad position) ----
    {
        const int m16 = tid & 15;
        const int g2 = m16 & 3, j2 = m16 >> 2;
        const int mm = g2 * 3 + j2;          // valid only when j2<3
        const bool live = (j2 < 3);
        const float w0 = live ? w0s[mm] : 0.f;
        const float w1 = live ? w1s[mm] : 0.f;
        const float kq = live ? kqs[mm] : 0.f;
        for (int t0 = (tid >> 4); t0 < Tn; t0 += 4) {
            const float2 x = xs[t0];
            zbuf[t0 * 16 + m16] = live ? fmaf(x.x, w0, fmaf(x.y, w1, kq)) * INV2PI : 0.f;
        }
        if (tid < 32) zbuf[Tn * 16 + tid] = 0.f;   // rows 512,513: deterministic tail
        if (tid < 16) invSW16[tid] = live ? (1.f / swArr[mm]) : 0.f;
    }
    __syncthreads();

    // ---- serial recurrence, whole wave cooperates; h,c wave-uniform ----
    // Gate: per-lane [3/3] Pade in w=u^2; reciprocal via quadratic Chebyshev seed + 1 Newton
    //   (full-rate VALU, no trans op). Cell tanh [3/3] keeps v_rcp; SWl folded into numerator.
    // h is never computed in-loop: zacc(t+1) = base(t+1) + h(t)*SWl is saved per step and h
    // reconstructed in the epilogue as (zsave - base)*invSW.
    {
        const int l16 = tid & 15;
        const int g  = l16 & 3;        // gate = quad position
        const int jj = l16 >> 2;       // cos slot = quad index within row
        const float SWl = (jj < 3) ? swArr[g * 3 + jj] : 0.f;
        const bool isG2 = (g == 2);
        // numerator / denominator (R7-verified)
        const float cp0 = 945.f;
        const float cp1 = isG2 ? 105.f : 26.25f;
        const float cp2 = isG2 ? 1.f   : 0.0625f;
        const float cq0 = isG2 ? 945.f : 3780.f;
        const float cq1 = 420.f;
        const float cq2 = isG2 ? 15.f  : 3.75f;
        const float addA = isG2 ? 0.f  : 0.5f;
        // quadratic seed coeffs for 1/Qd on w in [0,1] (Cheb-node fit, rel err <= 1.4e-3)
        const float NA = isG2 ? 1.129352e-4f : 2.594063e-6f;
        const float NB = isG2 ? -4.440815e-4f : -2.922584e-5f;
        const float NC = isG2 ? 1.056778e-3f : 2.645420e-4f;
        // cell-tanh numerator coeffs with SWl folded in
        const float s0 = 10395.f * SWl, s1 = 1260.f * SWl, s2 = 21.f * SWl;

        float c = 0.f;
        int zoff = l16;
        float zacc = zbuf[zoff];        // z(0) = base(0) since h(-1)=0
        float zn   = zbuf[zoff + 16];   // base(1)
        float zsA = 0.f, zsB = 0.f;

        for (int blk = 0; blk < 8; ++blk) {
            #pragma unroll 32
            for (int t64 = 0; t64 < 64; ++t64) {
                const float zf = zbuf[zoff + 32];   // prefetch base(t+2) (padded, rows 512/513 zeroed)
                zoff += 16;
                // z in revolutions; gfx9+ v_cos range-reduces in HW
                const float pc = __builtin_amdgcn_cosf(zacc);
                // product of the 4 j-slot cosines (dead slot z=0 -> cos=1)
                const float p1v = pc * dppf<0x124>(pc);
                const float u   = p1v * dppf<0x128>(p1v);
                // gate nonlinearity: per-lane rational, division-free reciprocal
                const float w   = u * u;
                const float Pn  = fmaf(w, fmaf(w, cp2, cp1), cp0);
                const float Qd  = fmaf(w, fmaf(w, cq2, cq1), cq0);
                const float r0  = fmaf(w, fmaf(w, NA, NB), NC);    // seed ~ 1/Qd
                const float m1  = Qd * r0;
                const float r1  = r0 * (2.f - m1);                 // Newton -> rel err ~2e-6
                const float uP  = u * Pn;
                const float A   = fmaf(uP, r1, addA);
                // gather gates by quad broadcast
                const float fg = dppf<0x00>(A);
                const float ig = dppf<0x55>(A);
                const float gu = dppf<0xAA>(A);
                const float og = dppf<0xFF>(A);
                c = fmaf(fg, c, ig * gu);
                // cell tanh [3/3]; chain tail = single fma into zacc
                const float y2   = c * c;
                const float y2sq = y2 * y2;
                const float oc   = og * c;
                const float P2S  = fmaf(y2sq, s2, fmaf(y2, s1, s0));       // SWl-scaled numerator
                const float Q2   = fmaf(y2sq, (y2 + 210.f), fmaf(y2, 4725.f, 10395.f));
                const float rQ2  = __builtin_amdgcn_rcpf(Q2);
                const float mP   = oc * P2S;
                zacc = fmaf(mP, rQ2, zn);            // z(t+1) = h(t)*SWl + base(t+1)
                // save zacc on a lane whose column has SWl != 0 (for h reconstruction)
                if ((t64 & 15) < 12) { zsA = (tid == t64)     ? zacc : zsA; }
                else                 { zsB = (tid == t64 - 4) ? zacc : zsB; }
                zn = zf;
            }
            zsaveA[blk * 64 + tid] = zsA;
            zsaveB[blk * 64 + tid + 4] = zsB;   // valid only for lanes with (tid&15) in [8,11]
        }
    }
    __syncthreads();

    // ---- epilogue: h(t) = (zsave(t) - base(t+1)) * invSW;  out[t] = sigmoid(h*sumWc + bc) ----
    const float swc = sumWc, b0 = bc[0];
    for (int t = tid; t < Tn; t += 64) {
        const int cidx = t & 15;
        const bool good = (cidx < 12);
        const int ceff = good ? cidx : (cidx - 4);
        const float zs = good ? zsaveA[t] : zsaveB[t];
        const float h = (zs - zbuf[(t + 1) * 16 + ceff]) * invSW16[ceff];
        out[t] = fsig_hw(fmaf(h, swc, b0));
    }
}

extern "C" void kernel_launch(void* const* d_in, const int* in_sizes, int n_in,
                              void* d_out, int out_size, void* d_ws, size_t ws_size,
                              hipStream_t stream) {
    const float* seq = (const float*)d_in[0];
    const float* Wf  = (const float*)d_in[1];
    const float* bf  = (const float*)d_in[2];
    const float* pf  = (const float*)d_in[3];
    const float* Wi  = (const float*)d_in[4];
    const float* bi  = (const float*)d_in[5];
    const float* pi  = (const float*)d_in[6];
    const float* Wu  = (const float*)d_in[7];
    const float* bu  = (const float*)d_in[8];
    const float* pu  = (const float*)d_in[9];
    const float* Wo  = (const float*)d_in[10];
    const float* bo  = (const float*)d_in[11];
    const float* po  = (const float*)d_in[12];
    const float* Wc  = (const float*)d_in[13];
    const float* bc  = (const float*)d_in[14];
    float* out = (float*)d_out;

    fraud_lstm_kernel<<<1, 64, 0, stream>>>(seq, Wf, bf, pf, Wi, bi, pi,
                                            Wu, bu, pu, Wo, bo, po, Wc, bc, out);
}

// Round 9
// 57.252 us; speedup vs baseline: 11.3145x; 1.0117x over previous
//
#include <hip/hip_runtime.h>

#define Tn 512
#define Bn 2048
#define Dn 2
#define NQn 4

#define INV2PI 0.15915494309189535f   // 1/(2*pi)
#define L2E    1.4426950408889634f    // log2(e)

__device__ __forceinline__ float fsig_hw(float x) {
    return __builtin_amdgcn_rcpf(1.f + __builtin_amdgcn_exp2f(-x * L2E));
}
// full-rate DPP permute; CTRL 0x00-0xFF = quad_perm, 0x121-0x12F = row_ror
template<int CTRL>
__device__ __forceinline__ float dppf(float x) {
    return __int_as_float(__builtin_amdgcn_mov_dpp(__float_as_int(x), CTRL, 0xF, 0xF, true));
}

__launch_bounds__(64)
__global__ void fraud_lstm_kernel(
    const float* __restrict__ seq,
    const float* __restrict__ Wf, const float* __restrict__ bf, const float* __restrict__ pf,
    const float* __restrict__ Wi, const float* __restrict__ bi, const float* __restrict__ pi,
    const float* __restrict__ Wu, const float* __restrict__ bu, const float* __restrict__ pu,
    const float* __restrict__ Wo, const float* __restrict__ bo, const float* __restrict__ po,
    const float* __restrict__ Wc, const float* __restrict__ bc,
    float* __restrict__ out)
{
    __shared__ float swArr[12], w0s[12], w1s[12], kqs[12];
    __shared__ float2 xs[Tn];
    __shared__ float zbuf[(Tn + 18) * 16];  // z-base rows 0..529 (rows >=512 zeroed)
    __shared__ float zsbuf[Tn * 16 + 64];   // zsbuf[t*16+c] (c<16) = z(t+1) col c after program-order writes
    __shared__ float sumWc;

    const int tid = threadIdx.x;
    const float* Wg[4] = {Wf, Wi, Wu, Wo};
    const float* bg[4] = {bf, bi, bu, bo};
    const float* pg[4] = {pf, pi, pu, po};

    // ---- stage x[t] = seq[t, B-1, 0:2] into LDS ----
    for (int t = tid; t < Tn; t += 64) {
        const float* p = seq + (size_t)t * (Bn * Dn) + (size_t)(Bn - 1) * Dn;
        xs[t] = make_float2(p[0], p[1]);
    }

    // ---- reduce weights: swArr[m] = (sum_j Wg[g][(Dn+j)*NQ+q]) / 2pi, m = g*3+(q-1) ----
    #pragma unroll
    for (int m = 0; m < 12; ++m) {
        const int g = m / 3, q = 1 + (m % 3);
        float v = Wg[g][(Dn + tid) * NQn + q];
        #pragma unroll
        for (int off = 32; off > 0; off >>= 1) v += __shfl_down(v, off, 64);
        if (tid == 0) {
            swArr[m] = v * INV2PI;
            w0s[m]   = Wg[g][0 * NQn + q];
            w1s[m]   = Wg[g][1 * NQn + q];
            kqs[m]   = bg[g][q] + pg[g][q];
        }
    }
    {
        float v = Wc[tid];
        #pragma unroll
        for (int off = 32; off > 0; off >>= 1) v += __shfl_down(v, off, 64);
        if (tid == 0) sumWc = v;
    }
    __syncthreads();

    // ---- parallel precompute zbuf: column m16 = j*4 + g (gate g in quad position) ----
    {
        const int m16 = tid & 15;
        const int g2 = m16 & 3, j2 = m16 >> 2;
        const int mm = g2 * 3 + j2;          // valid only when j2<3
        const bool live = (j2 < 3);
        const float w0 = live ? w0s[mm] : 0.f;
        const float w1 = live ? w1s[mm] : 0.f;
        const float kq = live ? kqs[mm] : 0.f;
        for (int t0 = (tid >> 4); t0 < Tn; t0 += 4) {
            const float2 x = xs[t0];
            zbuf[t0 * 16 + m16] = live ? fmaf(x.x, w0, fmaf(x.y, w1, kq)) * INV2PI : 0.f;
        }
        for (int i = tid; i < 18 * 16; i += 64) zbuf[Tn * 16 + i] = 0.f;  // rows 512..529
    }
    __syncthreads();

    // ---- serial recurrence, whole wave cooperates; h,c wave-uniform ----
    // Gate: per-lane [3/3] Pade in w=u^2, reciprocal by quadratic Cheb seed + 1 Newton (no trans).
    // Cell tanh [3/3] keeps v_rcp; SWl folded into numerator.
    // z-bases double-buffered in registers (16-step bursts of ds_read); zacc written to zsbuf
    // every step by ALL lanes (distinct addrs; lane<16 value is last in program order per slot).
    {
        const int l16 = tid & 15;
        const int g  = l16 & 3;        // gate = quad position
        const int jj = l16 >> 2;       // cos slot = quad index within row
        const float SWl = (jj < 3) ? swArr[g * 3 + jj] : 0.f;
        const bool isG2 = (g == 2);
        const float cp0 = 945.f;
        const float cp1 = isG2 ? 105.f : 26.25f;
        const float cp2 = isG2 ? 1.f   : 0.0625f;
        const float cq0 = isG2 ? 945.f : 3780.f;
        const float cq1 = 420.f;
        const float cq2 = isG2 ? 15.f  : 3.75f;
        const float addA = isG2 ? 0.f  : 0.5f;
        // quadratic seed coeffs for 1/Qd on w in [0,1] (Cheb-node fit, rel err <= 1.4e-3)
        const float NA = isG2 ? 1.129352e-4f : 2.594063e-6f;
        const float NB = isG2 ? -4.440815e-4f : -2.922584e-5f;
        const float NC = isG2 ? 1.056778e-3f : 2.645420e-4f;
        const float s0 = 10395.f * SWl, s1 = 1260.f * SWl, s2 = 21.f * SWl;

        float c = 0.f;
        float zacc = zbuf[l16];         // z(0) = base(0) since h(-1)=0
        float za[16], zb2[16];
        #pragma unroll
        for (int k = 0; k < 16; ++k) za[k] = zbuf[(k + 1) * 16 + l16];   // rows 1..16
        int ldoff = 17 * 16 + l16;      // next burst: rows 17..32
        int woff = tid;                 // zsbuf write index, step 0

#define STEP(ZNV)                                                            \
        {                                                                    \
            const float pc  = __builtin_amdgcn_cosf(zacc);                   \
            const float p1v = pc * dppf<0x124>(pc);                          \
            const float u   = p1v * dppf<0x128>(p1v);                        \
            const float w   = u * u;                                         \
            const float Qd  = fmaf(w, fmaf(w, cq2, cq1), cq0);               \
            const float r0  = fmaf(w, fmaf(w, NA, NB), NC);                  \
            const float Pn  = fmaf(w, fmaf(w, cp2, cp1), cp0);               \
            const float uPr = (u * Pn) * r0;                                 \
            const float m1  = Qd * r0;                                       \
            const float A   = fmaf(uPr, (2.f - m1), addA);                   \
            const float fg  = dppf<0x00>(A);                                 \
            const float ig  = dppf<0x55>(A);                                 \
            const float gu  = dppf<0xAA>(A);                                 \
            const float og  = dppf<0xFF>(A);                                 \
            c = fmaf(fg, c, ig * gu);                                        \
            const float y2   = c * c;                                        \
            const float y2sq = y2 * y2;                                      \
            const float oc   = og * c;                                       \
            const float P2S  = fmaf(y2sq, s2, fmaf(y2, s1, s0));             \
            const float Q2   = fmaf(y2sq, (y2 + 210.f), fmaf(y2, 4725.f, 10395.f)); \
            const float rQ2  = __builtin_amdgcn_rcpf(Q2);                    \
            zacc = fmaf(oc * P2S, rQ2, ZNV);                                 \
            zsbuf[woff] = zacc;                                              \
            woff += 16;                                                      \
        }

        for (int sbp = 0; sbp < 16; ++sbp) {
            // body A: prefetch next 16 rows, compute 16 steps from za
            #pragma unroll
            for (int k = 0; k < 16; ++k) zb2[k] = zbuf[ldoff + k * 16];
            #pragma unroll
            for (int k = 0; k < 16; ++k) STEP(za[k]);
            ldoff += 256;
            // body B: prefetch next 16 rows, compute 16 steps from zb2
            #pragma unroll
            for (int k = 0; k < 16; ++k) za[k] = zbuf[ldoff + k * 16];
            #pragma unroll
            for (int k = 0; k < 16; ++k) STEP(zb2[k]);
            ldoff += 256;
        }
#undef STEP
    }
    __syncthreads();

    // ---- epilogue: pick best column (max |SW|), reconstruct h, write sigmoid ----
    {
        int best = 0; float bv = 0.f;
        #pragma unroll
        for (int m = 0; m < 12; ++m) {
            const float a = fabsf(swArr[m]);
            if (a > bv) { bv = a; best = m; }
        }
        const int cbest = (best % 3) * 4 + (best / 3);   // column = j*4 + g
        const float invSWb = 1.f / swArr[best];
        const float swc = sumWc, b0 = bc[0];
        for (int t = tid; t < Tn; t += 64) {
            const float zs = zsbuf[t * 16 + cbest];             // = z(t+1) col cbest
            const float h  = (zs - zbuf[(t + 1) * 16 + cbest]) * invSWb;
            out[t] = fsig_hw(fmaf(h, swc, b0));
        }
    }
}

extern "C" void kernel_launch(void* const* d_in, const int* in_sizes, int n_in,
                              void* d_out, int out_size, void* d_ws, size_t ws_size,
                              hipStream_t stream) {
    const float* seq = (const float*)d_in[0];
    const float* Wf  = (const float*)d_in[1];
    const float* bf  = (const float*)d_in[2];
    const float* pf  = (const float*)d_in[3];
    const float* Wi  = (const float*)d_in[4];
    const float* bi  = (const float*)d_in[5];
    const float* pi  = (const float*)d_in[6];
    const float* Wu  = (const float*)d_in[7];
    const float* bu  = (const float*)d_in[8];
    const float* pu  = (const float*)d_in[9];
    const float* Wo  = (const float*)d_in[10];
    const float* bo  = (const float*)d_in[11];
    const float* po  = (const float*)d_in[12];
    const float* Wc  = (const float*)d_in[13];
    const float* bc  = (const float*)d_in[14];
    float* out = (float*)d_out;

    fraud_lstm_kernel<<<1, 64, 0, stream>>>(seq, Wf, bf, pf, Wi, bi, pi,
                                            Wu, bu, pu, Wo, bo, po, Wc, bc, out);
}

// Round 10
// 55.133 us; speedup vs baseline: 11.7493x; 1.0384x over previous
//
#include <hip/hip_runtime.h>

#define Tn 512
#define Bn 2048
#define Dn 2
#define NQn 4

#define INV2PI 0.15915494309189535f   // 1/(2*pi)
#define L2E    1.4426950408889634f    // log2(e)

__device__ __forceinline__ float fsig_hw(float x) {
    return __builtin_amdgcn_rcpf(1.f + __builtin_amdgcn_exp2f(-x * L2E));
}
// full-rate DPP permute; CTRL 0x00-0xFF = quad_perm, 0x121-0x12F = row_ror
template<int CTRL>
__device__ __forceinline__ float dppf(float x) {
    return __int_as_float(__builtin_amdgcn_mov_dpp(__float_as_int(x), CTRL, 0xF, 0xF, true));
}

__launch_bounds__(64)
__global__ void fraud_lstm_kernel(
    const float* __restrict__ seq,
    const float* __restrict__ Wf, const float* __restrict__ bf, const float* __restrict__ pf,
    const float* __restrict__ Wi, const float* __restrict__ bi, const float* __restrict__ pi,
    const float* __restrict__ Wu, const float* __restrict__ bu, const float* __restrict__ pu,
    const float* __restrict__ Wo, const float* __restrict__ bo, const float* __restrict__ po,
    const float* __restrict__ Wc, const float* __restrict__ bc,
    float* __restrict__ out)
{
    __shared__ float swArr[12], w0s[12], w1s[12], kqs[12];
    __shared__ float W0c[16], W1c[16], kqc[16];   // sign-combined column weights
    __shared__ float2 xs[Tn];
    __shared__ float zbuf[(Tn + 18) * 16];  // cos-sum bases, 16 cols = (gate, combo); rows >=512 zeroed
    __shared__ float hbufx[Tn + 80];        // h per step (lane0) + dump area
    __shared__ float sumWc;

    const int tid = threadIdx.x;
    const float* Wg[4] = {Wf, Wi, Wu, Wo};
    const float* bg[4] = {bf, bi, bu, bo};
    const float* pg[4] = {pf, pi, pu, po};

    // ---- stage x[t] = seq[t, B-1, 0:2] into LDS ----
    for (int t = tid; t < Tn; t += 64) {
        const float* p = seq + (size_t)t * (Bn * Dn) + (size_t)(Bn - 1) * Dn;
        xs[t] = make_float2(p[0], p[1]);
    }

    // ---- reduce weights: swArr[m] = (sum_j Wg[g][(Dn+j)*NQ+q]) / 2pi, m = g*3+(q-1) ----
    #pragma unroll
    for (int m = 0; m < 12; ++m) {
        const int g = m / 3, q = 1 + (m % 3);
        float v = Wg[g][(Dn + tid) * NQn + q];
        #pragma unroll
        for (int off = 32; off > 0; off >>= 1) v += __shfl_down(v, off, 64);
        if (tid == 0) {
            swArr[m] = v * INV2PI;
            w0s[m]   = Wg[g][0 * NQn + q];
            w1s[m]   = Wg[g][1 * NQn + q];
            kqs[m]   = bg[g][q] + pg[g][q];
        }
    }
    {
        float v = Wc[tid];
        #pragma unroll
        for (int off = 32; off > 0; off >>= 1) v += __shfl_down(v, off, 64);
        if (tid == 0) sumWc = v;
    }
    __syncthreads();

    // ---- sign-combined column weights: col = 2*l8 + ab, l8 = 4*?? (g = l8&3, s2 = l8>>2) ----
    // combos: (s2,ab)=(0,0):+++  (0,1):++-  (1,0):+-+  (1,1):-++
    if (tid < 16) {
        const int col = tid, l8 = col >> 1, ab = col & 1;
        const int g = l8 & 3, s2 = l8 >> 2;
        const float sg0 = (s2 == 1 && ab == 1) ? -1.f : 1.f;
        const float sg1 = (s2 == 1 && ab == 0) ? -1.f : 1.f;
        const float sg2 = (s2 == 0 && ab == 1) ? -1.f : 1.f;
        const int m = g * 3;
        W0c[col] = sg0 * w0s[m] + sg1 * w0s[m + 1] + sg2 * w0s[m + 2];
        W1c[col] = sg0 * w1s[m] + sg1 * w1s[m + 1] + sg2 * w1s[m + 2];
        kqc[col] = sg0 * kqs[m] + sg1 * kqs[m + 1] + sg2 * kqs[m + 2];
    }
    __syncthreads();

    // ---- parallel precompute zbuf: B_col(t) = (x.W0c + x2.W1c + kqc)/2pi ----
    {
        const int col = tid & 15;
        const float w0 = W0c[col], w1 = W1c[col], kq = kqc[col];
        for (int t0 = (tid >> 4); t0 < Tn; t0 += 4) {
            const float2 x = xs[t0];
            zbuf[t0 * 16 + col] = fmaf(x.x, w0, fmaf(x.y, w1, kq)) * INV2PI;
        }
        for (int i = tid; i < 18 * 16; i += 64) zbuf[Tn * 16 + i] = 0.f;  // rows 512..529
    }
    __syncthreads();

    // ---- serial recurrence; pre_g = (1/4) sum of 4 cos (product-to-sum identity) ----
    // lane l8 = tid&7: gate g = l8&3, pair s2 = l8>>2; holds combos {2*s2, 2*s2+1} (2 cos in-lane).
    // 4-sum completed by ONE row_ror:4 dpp-add (8-periodic redundancy -> direction-immune).
    // Gate: [3/3] Pade in w = s^2 (1/4 and 1/16 scale folded into coeffs), reciprocal via
    // quadratic Cheb seed + 1 Newton (no trans). Cell tanh [3/3] + v_rcp; W folded off-chain.
    {
        const int l8 = tid & 7;
        const int g  = l8 & 3;
        const int s2 = l8 >> 2;
        const bool isG2 = (g == 2);
        const int m = g * 3;
        const float sw0 = swArr[m], sw1 = swArr[m + 1], sw2 = swArr[m + 2];
        const float WAc = s2 ? (sw0 - sw1 + sw2) : (sw0 + sw1 + sw2);
        const float WBc = s2 ? (-sw0 + sw1 + sw2) : (sw0 + sw1 - sw2);
        // gate Pade coeffs on w = s^2 in [0,16]  (A = s*Pn(w)/Qd(w) + addA)
        const float cp0 = 236.25f;                                  // 945/4 (both)
        const float cp1 = isG2 ? 1.640625f       : 0.41015625f;     // /64
        const float cp2 = isG2 ? 9.765625e-4f    : 6.1035156e-5f;   // /1024
        const float cq0 = isG2 ? 945.f           : 3780.f;
        const float cq1 = 26.25f;                                   // 420/16 (both)
        const float cq2 = isG2 ? 5.859375e-2f    : 1.46484375e-2f;  // /256
        const float addA = isG2 ? 0.f : 0.5f;
        // reciprocal seed for 1/Qd on w in [0,16] (R8 fit, rescaled)
        const float NA = isG2 ? 4.41153125e-7f  : 1.01330586e-8f;
        const float NB = isG2 ? -2.77550938e-5f : -1.82661500e-6f;
        const float NC = isG2 ? 1.056778e-3f    : 2.645420e-4f;

        const float2* zb2p = (const float2*)zbuf;
        float c = 0.f;
        float2 z0 = zb2p[l8];           // row 0
        float zaccA = z0.x, zaccB = z0.y;   // z(0) = base(0) since h(-1)=0
        float2 za2[16], zb2[16];
        #pragma unroll
        for (int k = 0; k < 16; ++k) za2[k] = zb2p[(k + 1) * 8 + l8];   // rows 1..16
        int ldoff = 17 * 8 + l8;        // next burst: rows 17..32 (float2 units)
        int hidx  = (tid == 0) ? 0 : (Tn + 1 + tid);
        const int hstep = (tid == 0) ? 1 : 0;

#define STEP(ZN2)                                                            \
        {                                                                    \
            const float cA = __builtin_amdgcn_cosf(zaccA);                   \
            const float cB = __builtin_amdgcn_cosf(zaccB);                   \
            const float sP = cA + cB;                                        \
            const float s  = sP + dppf<0x124>(sP);                           \
            const float w2 = s * s;                                          \
            const float Qd = fmaf(w2, fmaf(w2, cq2, cq1), cq0);              \
            const float r0 = fmaf(w2, fmaf(w2, NA, NB), NC);                 \
            const float Pn = fmaf(w2, fmaf(w2, cp2, cp1), cp0);              \
            const float uPr = (s * Pn) * r0;                                 \
            const float m1 = Qd * r0;                                        \
            const float A  = fmaf(uPr, (2.f - m1), addA);                    \
            const float fg = dppf<0x00>(A);                                  \
            const float ig = dppf<0x55>(A);                                  \
            const float gu = dppf<0xAA>(A);                                  \
            const float og = dppf<0xFF>(A);                                  \
            c = fmaf(fg, c, ig * gu);                                        \
            const float y  = c * c;                                          \
            const float Q2 = fmaf(y, fmaf(y, (y + 210.f), 4725.f), 10395.f); \
            const float rQ2 = __builtin_amdgcn_rcpf(Q2);                     \
            const float P2 = fmaf(y, fmaf(y, 21.f, 1260.f), 10395.f);        \
            const float ocP = (og * c) * P2;                                 \
            const float kA = ocP * WAc;                                      \
            const float kB = ocP * WBc;                                      \
            zaccA = fmaf(kA, rQ2, (ZN2).x);                                  \
            zaccB = fmaf(kB, rQ2, (ZN2).y);                                  \
            hbufx[hidx] = ocP * rQ2;                                         \
            hidx += hstep;                                                   \
        }

        for (int sbp = 0; sbp < 16; ++sbp) {
            #pragma unroll
            for (int k = 0; k < 16; ++k) zb2[k] = zb2p[ldoff + k * 8];
            #pragma unroll
            for (int k = 0; k < 16; ++k) STEP(za2[k]);
            ldoff += 128;
            #pragma unroll
            for (int k = 0; k < 16; ++k) za2[k] = zb2p[ldoff + k * 8];
            #pragma unroll
            for (int k = 0; k < 16; ++k) STEP(zb2[k]);
            ldoff += 128;
        }
#undef STEP
    }
    __syncthreads();

    // ---- epilogue: out[t] = sigmoid(h[t]*sum(Wc) + bc) ----
    const float swc = sumWc, b0 = bc[0];
    for (int t = tid; t < Tn; t += 64) {
        out[t] = fsig_hw(fmaf(hbufx[t], swc, b0));
    }
}

extern "C" void kernel_launch(void* const* d_in, const int* in_sizes, int n_in,
                              void* d_out, int out_size, void* d_ws, size_t ws_size,
                              hipStream_t stream) {
    const float* seq = (const float*)d_in[0];
    const float* Wf  = (const float*)d_in[1];
    const float* bf  = (const float*)d_in[2];
    const float* pf  = (const float*)d_in[3];
    const float* Wi  = (const float*)d_in[4];
    const float* bi  = (const float*)d_in[5];
    const float* pi  = (const float*)d_in[6];
    const float* Wu  = (const float*)d_in[7];
    const float* bu  = (const float*)d_in[8];
    const float* pu  = (const float*)d_in[9];
    const float* Wo  = (const float*)d_in[10];
    const float* bo  = (const float*)d_in[11];
    const float* po  = (const float*)d_in[12];
    const float* Wc  = (const float*)d_in[13];
    const float* bc  = (const float*)d_in[14];
    float* out = (float*)d_out;

    fraud_lstm_kernel<<<1, 64, 0, stream>>>(seq, Wf, bf, pf, Wi, bi, pi,
                                            Wu, bu, pu, Wo, bo, po, Wc, bc, out);
}

// Round 11
// 50.263 us; speedup vs baseline: 12.8878x; 1.0969x over previous
//
#include <hip/hip_runtime.h>

#define Tn 512
#define Bn 2048
#define Dn 2
#define NQn 4

#define INV2PI 0.15915494309189535f   // 1/(2*pi)
#define L2E    1.4426950408889634f    // log2(e)

__device__ __forceinline__ float fsig_hw(float x) {
    return __builtin_amdgcn_rcpf(1.f + __builtin_amdgcn_exp2f(-x * L2E));
}
// full-rate DPP permute; CTRL 0x00-0xFF = quad_perm, 0x121-0x12F = row_ror
template<int CTRL>
__device__ __forceinline__ float dppf(float x) {
    return __int_as_float(__builtin_amdgcn_mov_dpp(__float_as_int(x), CTRL, 0xF, 0xF, true));
}

__launch_bounds__(256)
__global__ void fraud_lstm_kernel(
    const float* __restrict__ seq,
    const float* __restrict__ Wf, const float* __restrict__ bf, const float* __restrict__ pf,
    const float* __restrict__ Wi, const float* __restrict__ bi, const float* __restrict__ pi,
    const float* __restrict__ Wu, const float* __restrict__ bu, const float* __restrict__ pu,
    const float* __restrict__ Wo, const float* __restrict__ bo, const float* __restrict__ po,
    const float* __restrict__ Wc, const float* __restrict__ bc,
    float* __restrict__ out)
{
    __shared__ float swArr[12], w0s[12], w1s[12], kqs[12];
    __shared__ float W0c[16], W1c[16], kqc[16];   // sign-combined column weights
    __shared__ float2 xs[Tn];
    __shared__ float zbuf[(Tn + 18) * 16];  // cos-sum bases, 16 cols = (gate, combo); rows >=512 zeroed
    __shared__ float hbufx[Tn + 80];        // h per step (lane0) + dump area
    __shared__ float sumWc;

    const int tid = threadIdx.x;
    const int lane = tid & 63;
    const int wav = tid >> 6;
    const float* Wg[4] = {Wf, Wi, Wu, Wo};
    const float* bg[4] = {bf, bi, bu, bo};
    const float* pg[4] = {pf, pi, pu, po};

    // ---- stage x[t] = seq[t, B-1, 0:2] into LDS (256 threads -> 2 rounds) ----
    for (int t = tid; t < Tn; t += 256) {
        const float* p = seq + (size_t)t * (Bn * Dn) + (size_t)(Bn - 1) * Dn;
        xs[t] = make_float2(p[0], p[1]);
    }

    // ---- reduce weights, split across waves: wave w owns m = 3w..3w+2; wave 3 also Wc ----
    #pragma unroll
    for (int mi = 0; mi < 3; ++mi) {
        const int m = wav * 3 + mi;
        const int g = m / 3, q = 1 + (m % 3);
        float v = Wg[g][(Dn + lane) * NQn + q];
        #pragma unroll
        for (int off = 32; off > 0; off >>= 1) v += __shfl_down(v, off, 64);
        if (lane == 0) {
            swArr[m] = v * INV2PI;
            w0s[m]   = Wg[g][0 * NQn + q];
            w1s[m]   = Wg[g][1 * NQn + q];
            kqs[m]   = bg[g][q] + pg[g][q];
        }
    }
    if (wav == 3) {
        float v = Wc[lane];
        #pragma unroll
        for (int off = 32; off > 0; off >>= 1) v += __shfl_down(v, off, 64);
        if (lane == 0) sumWc = v;
    }
    __syncthreads();

    // ---- sign-combined column weights: col = 2*l8 + ab (g = l8&3, s2 = l8>>2) ----
    // combos: (s2,ab)=(0,0):+++  (0,1):++-  (1,0):+-+  (1,1):-++
    if (tid < 16) {
        const int col = tid, l8 = col >> 1, ab = col & 1;
        const int g = l8 & 3, s2 = l8 >> 2;
        const float sg0 = (s2 == 1 && ab == 1) ? -1.f : 1.f;
        const float sg1 = (s2 == 1 && ab == 0) ? -1.f : 1.f;
        const float sg2 = (s2 == 0 && ab == 1) ? -1.f : 1.f;
        const int m = g * 3;
        W0c[col] = sg0 * w0s[m] + sg1 * w0s[m + 1] + sg2 * w0s[m + 2];
        W1c[col] = sg0 * w1s[m] + sg1 * w1s[m + 1] + sg2 * w1s[m + 2];
        kqc[col] = sg0 * kqs[m] + sg1 * kqs[m + 1] + sg2 * kqs[m + 2];
    }
    __syncthreads();

    // ---- parallel precompute zbuf: B_col(t) = (x.W0c + x2.W1c + kqc)/2pi (256 thr -> 32 iters) ----
    {
        const int col = tid & 15;
        const float w0 = W0c[col], w1 = W1c[col], kq = kqc[col];
        for (int t0 = (tid >> 4); t0 < Tn; t0 += 16) {
            const float2 x = xs[t0];
            zbuf[t0 * 16 + col] = fmaf(x.x, w0, fmaf(x.y, w1, kq)) * INV2PI;
        }
        for (int i = tid; i < 18 * 16; i += 256) zbuf[Tn * 16 + i] = 0.f;  // rows 512..529
    }
    __syncthreads();

    // ---- serial recurrence on wave 0 only; waves 1-3 sleep at the barrier ----
    // pre_g = (1/4) sum of 4 cos (product-to-sum identity); lane l8: gate g=l8&3, pair s2=l8>>2.
    // 4-sum completed by ONE row_ror:4 dpp-add (8-periodic redundancy -> direction-immune).
    // Gate: [3/3] Pade in w = s^2 (scales folded), reciprocal via quadratic Cheb seed + 1 Newton.
    // Cell tanh [3/3] + v_rcp; W folded off-chain; z-bases double-buffered in registers.
    if (tid < 64) {
        const int l8 = tid & 7;
        const int g  = l8 & 3;
        const int s2 = l8 >> 2;
        const bool isG2 = (g == 2);
        const int m = g * 3;
        const float sw0 = swArr[m], sw1 = swArr[m + 1], sw2 = swArr[m + 2];
        const float WAc = s2 ? (sw0 - sw1 + sw2) : (sw0 + sw1 + sw2);
        const float WBc = s2 ? (-sw0 + sw1 + sw2) : (sw0 + sw1 - sw2);
        // gate Pade coeffs on w = s^2 in [0,16]  (A = s*Pn(w)/Qd(w) + addA)
        const float cp0 = 236.25f;                                  // 945/4 (both)
        const float cp1 = isG2 ? 1.640625f       : 0.41015625f;     // /64
        const float cp2 = isG2 ? 9.765625e-4f    : 6.1035156e-5f;   // /1024
        const float cq0 = isG2 ? 945.f           : 3780.f;
        const float cq1 = 26.25f;                                   // 420/16 (both)
        const float cq2 = isG2 ? 5.859375e-2f    : 1.46484375e-2f;  // /256
        const float addA = isG2 ? 0.f : 0.5f;
        // reciprocal seed for 1/Qd on w in [0,16]
        const float NA = isG2 ? 4.41153125e-7f  : 1.01330586e-8f;
        const float NB = isG2 ? -2.77550938e-5f : -1.82661500e-6f;
        const float NC = isG2 ? 1.056778e-3f    : 2.645420e-4f;

        const float2* zb2p = (const float2*)zbuf;
        float c = 0.f;
        float2 z0 = zb2p[l8];           // row 0
        float zaccA = z0.x, zaccB = z0.y;   // z(0) = base(0) since h(-1)=0
        float2 za2[16], zb2[16];
        #pragma unroll
        for (int k = 0; k < 16; ++k) za2[k] = zb2p[(k + 1) * 8 + l8];   // rows 1..16
        int ldoff = 17 * 8 + l8;        // next burst: rows 17..32 (float2 units)
        int hidx  = (tid == 0) ? 0 : (Tn + 1 + tid);
        const int hstep = (tid == 0) ? 1 : 0;

#define STEP(ZN2)                                                            \
        {                                                                    \
            const float cA = __builtin_amdgcn_cosf(zaccA);                   \
            const float cB = __builtin_amdgcn_cosf(zaccB);                   \
            const float sP = cA + cB;                                        \
            const float s  = sP + dppf<0x124>(sP);                           \
            const float w2 = s * s;                                          \
            const float Qd = fmaf(w2, fmaf(w2, cq2, cq1), cq0);              \
            const float r0 = fmaf(w2, fmaf(w2, NA, NB), NC);                 \
            const float Pn = fmaf(w2, fmaf(w2, cp2, cp1), cp0);              \
            const float uPr = (s * Pn) * r0;                                 \
            const float m1 = Qd * r0;                                        \
            const float A  = fmaf(uPr, (2.f - m1), addA);                    \
            const float fg = dppf<0x00>(A);                                  \
            const float ig = dppf<0x55>(A);                                  \
            const float gu = dppf<0xAA>(A);                                  \
            const float og = dppf<0xFF>(A);                                  \
            c = fmaf(fg, c, ig * gu);                                        \
            const float y  = c * c;                                          \
            const float Q2 = fmaf(y, fmaf(y, (y + 210.f), 4725.f), 10395.f); \
            const float rQ2 = __builtin_amdgcn_rcpf(Q2);                     \
            const float P2 = fmaf(y, fmaf(y, 21.f, 1260.f), 10395.f);        \
            const float ocP = (og * c) * P2;                                 \
            const float kA = ocP * WAc;                                      \
            const float kB = ocP * WBc;                                      \
            zaccA = fmaf(kA, rQ2, (ZN2).x);                                  \
            zaccB = fmaf(kB, rQ2, (ZN2).y);                                  \
            hbufx[hidx] = ocP * rQ2;                                         \
            hidx += hstep;                                                   \
        }

        for (int sbp = 0; sbp < 16; ++sbp) {
            #pragma unroll
            for (int k = 0; k < 16; ++k) zb2[k] = zb2p[ldoff + k * 8];
            #pragma unroll
            for (int k = 0; k < 16; ++k) STEP(za2[k]);
            ldoff += 128;
            #pragma unroll
            for (int k = 0; k < 16; ++k) za2[k] = zb2p[ldoff + k * 8];
            #pragma unroll
            for (int k = 0; k < 16; ++k) STEP(zb2[k]);
            ldoff += 128;
        }
#undef STEP
    }
    __syncthreads();

    // ---- epilogue: out[t] = sigmoid(h[t]*sum(Wc) + bc) (256 threads -> 2 iters) ----
    const float swc = sumWc, b0 = bc[0];
    for (int t = tid; t < Tn; t += 256) {
        out[t] = fsig_hw(fmaf(hbufx[t], swc, b0));
    }
}

extern "C" void kernel_launch(void* const* d_in, const int* in_sizes, int n_in,
                              void* d_out, int out_size, void* d_ws, size_t ws_size,
                              hipStream_t stream) {
    const float* seq = (const float*)d_in[0];
    const float* Wf  = (const float*)d_in[1];
    const float* bf  = (const float*)d_in[2];
    const float* pf  = (const float*)d_in[3];
    const float* Wi  = (const float*)d_in[4];
    const float* bi  = (const float*)d_in[5];
    const float* pi  = (const float*)d_in[6];
    const float* Wu  = (const float*)d_in[7];
    const float* bu  = (const float*)d_in[8];
    const float* pu  = (const float*)d_in[9];
    const float* Wo  = (const float*)d_in[10];
    const float* bo  = (const float*)d_in[11];
    const float* po  = (const float*)d_in[12];
    const float* Wc  = (const float*)d_in[13];
    const float* bc  = (const float*)d_in[14];
    float* out = (float*)d_out;

    fraud_lstm_kernel<<<1, 256, 0, stream>>>(seq, Wf, bf, pf, Wi, bi, pi,
                                             Wu, bu, pu, Wo, bo, po, Wc, bc, out);
}